// Round 12
// baseline (235.520 us; speedup 1.0000x reference)
//
#include <hip/hip_runtime.h>
#include <stdint.h>

typedef unsigned short u16;
typedef short short8 __attribute__((ext_vector_type(8)));
typedef float f32x4 __attribute__((ext_vector_type(4)));
typedef uint32_t u32x4 __attribute__((ext_vector_type(4)));

#define S_LEN 2048
#define NQH 32
#define NKH 8
#define DHD 64
#define MNEG -1.0e30f

__device__ __forceinline__ float b2f(u16 u){
  union { uint32_t i; float f; } c; c.i = ((uint32_t)u) << 16; return c.f;
}
__device__ __forceinline__ u16 f2b(float f){
  union { float f; uint32_t i; } c; c.f = f;
  uint32_t r = c.i + 0x7fffu + ((c.i >> 16) & 1u);
  return (u16)(r >> 16);
}
__device__ __forceinline__ uint32_t cvt_pk_bf16(float lo, float hi){
  uint32_t r;
  asm("v_cvt_pk_bf16_f32 %0, %1, %2" : "=v"(r) : "v"(lo), "v"(hi));
  return r;
}
__device__ __forceinline__ void gload_lds16(const void* g, void* l){
  __builtin_amdgcn_global_load_lds((const __attribute__((address_space(1))) uint32_t*)g,
                                   (__attribute__((address_space(3))) uint32_t*)l, 16, 0, 0);
}

// ---------------- fused fp32 -> bf16 convert (hs | Wqkv | Wo) ----------------
__global__ __launch_bounds__(256) void cvt_all(const float* __restrict__ hs,
                                               const float* __restrict__ wq,
                                               const float* __restrict__ wo,
                                               u16* __restrict__ hsB,
                                               u16* __restrict__ wqB,
                                               u16* __restrict__ woB){
  int i = blockIdx.x * 256 + threadIdx.x;       // 4718592 float4 total
  const float* src; u16* dst; int off;
  if (i < 2097152)      { src = hs; dst = hsB; off = i; }
  else if (i < 3670016) { src = wq; dst = wqB; off = i - 2097152; }
  else                  { src = wo; dst = woB; off = i - 3670016; }
  float4 v = ((const float4*)src)[off];
  uint2 o;
  o.x = (uint32_t)f2b(v.x) | ((uint32_t)f2b(v.y) << 16);
  o.y = (uint32_t)f2b(v.z) | ((uint32_t)f2b(v.w) << 16);
  ((uint2*)dst)[off] = o;
}

// ---------------- bf16 GEMM: C[M][N] = A[M][K] * B[N][K]^T ----------------
template<int OUT_F32>
__global__ __launch_bounds__(256)
void gemm_bt(const u16* __restrict__ A, const u16* __restrict__ Bm,
             void* __restrict__ Cp, int N, int K)
{
  __shared__ alignas(16) u16 lA[128 * 64];
  __shared__ alignas(16) u16 lB[128 * 64];
  const int tid = threadIdx.x;
  const int w = tid >> 6, l = tid & 63;
  const int lg = l >> 4, lc = l & 15;
  const int wm = w >> 1, wn = w & 1;
  const int m0 = blockIdx.y * 128, n0 = blockIdx.x * 128;
  const int srow = l >> 3, sc = l & 7;
  const size_t ldb = (size_t)K * 2;   // row bytes
  f32x4 acc[4][4] = {};
  const int kiters = K >> 6;
  for (int kt = 0; kt < kiters; ++kt){
    __syncthreads();
#pragma unroll
    for (int i = 0; i < 4; ++i){
      const int row = (i * 4 + w) * 8 + srow;
      const int gc = ((sc ^ (row & 7)) << 4);
      gload_lds16((const char*)A + (size_t)(m0 + row) * ldb + (size_t)kt * 128 + gc,
                  (char*)lA + row * 128 + sc * 16);
    }
#pragma unroll
    for (int i = 0; i < 4; ++i){
      const int row = (i * 4 + w) * 8 + srow;
      const int gc = ((sc ^ (row & 7)) << 4);
      gload_lds16((const char*)Bm + (size_t)(n0 + row) * ldb + (size_t)kt * 128 + gc,
                  (char*)lB + row * 128 + sc * 16);
    }
    __syncthreads();
#pragma unroll
    for (int kk = 0; kk < 2; ++kk){
      short8 af[4], bfr[4];
#pragma unroll
      for (int mi = 0; mi < 4; ++mi){
        const int row = wm * 64 + mi * 16 + lc;
        const int cc = (kk * 4 + lg) ^ (row & 7);
        af[mi] = *(const short8*)((const char*)lA + row * 128 + cc * 16);
      }
#pragma unroll
      for (int ni = 0; ni < 4; ++ni){
        const int row = wn * 64 + ni * 16 + lc;
        const int cc = (kk * 4 + lg) ^ (row & 7);
        bfr[ni] = *(const short8*)((const char*)lB + row * 128 + cc * 16);
      }
#pragma unroll
      for (int mi = 0; mi < 4; ++mi)
#pragma unroll
        for (int ni = 0; ni < 4; ++ni)
          acc[mi][ni] = __builtin_amdgcn_mfma_f32_16x16x32_bf16(af[mi], bfr[ni], acc[mi][ni], 0, 0, 0);
    }
  }
  const int r0 = m0 + wm * 64 + lg * 4;
  const int c0 = n0 + wn * 64 + lc;
#pragma unroll
  for (int mi = 0; mi < 4; ++mi)
#pragma unroll
    for (int ni = 0; ni < 4; ++ni)
#pragma unroll
      for (int j = 0; j < 4; ++j){
        const size_t idx = (size_t)(r0 + mi * 16 + j) * (size_t)N + (size_t)(c0 + ni * 16);
        if (OUT_F32) ((float*)Cp)[idx] = acc[mi][ni][j];
        else         ((u16*)Cp)[idx]  = f2b(acc[mi][ni][j]);
      }
}

// ---------------- RoPE + scales; qkv[b][s][48][64] -> Q[b][h][s][64], K[b][kh][s][64] ----------------
// Q additionally folded by SM_SCALE*log2(e) so attention scores exit QK^T in exp2 domain.
__global__ __launch_bounds__(256)
void rope_kernel(const u16* __restrict__ qkv, const float* __restrict__ cosT,
                 const float* __restrict__ sinT, const float* __restrict__ phs,
                 u16* __restrict__ Qo, u16* __restrict__ Ko)
{
  int id = blockIdx.x * 256 + threadIdx.x;      // B*40*S*4 = 655360
  int b = (id >= 327680) ? 1 : 0;
  int rem = id - b * 327680;
  int head = rem >> 13;                         // 0..39
  int s = (rem >> 2) & 2047;
  int d0 = (rem & 3) << 4;                      // 0,16,32,48
  const u16* src = qkv + (((size_t)(b * S_LEN + s) * 48 + head) << 6);
  uint4 xa = *(const uint4*)(src + d0);
  uint4 xb = *(const uint4*)(src + d0 + 8);
  int d0p = (d0 + 32) & 63;
  uint4 pa = *(const uint4*)(src + d0p);
  uint4 pb = *(const uint4*)(src + d0p + 8);
  const float* cp = cosT + s * 64 + d0;
  const float* sp = sinT + s * 64 + d0;
  const float sgn = (d0 < 32) ? -1.f : 1.f;
  const float kscale = 0.18033688011112042f;    // SM_SCALE * log2(e)
  const float scale = (head < NQH) ? 1.2f * kscale * phs[b * NQH + head] : 1.2f;
  uint32_t xs[4] = {xa.x, xa.y, xa.z, xa.w};
  uint32_t xs2[4] = {xb.x, xb.y, xb.z, xb.w};
  uint32_t ps[4] = {pa.x, pa.y, pa.z, pa.w};
  uint32_t ps2[4] = {pb.x, pb.y, pb.z, pb.w};
  uint32_t ow[8];
#pragma unroll
  for (int k = 0; k < 4; ++k){
    float v0 = b2f((u16)(xs[k] & 0xffff)) * cp[2*k]   + sgn * b2f((u16)(ps[k] & 0xffff)) * sp[2*k];
    float v1 = b2f((u16)(xs[k] >> 16))    * cp[2*k+1] + sgn * b2f((u16)(ps[k] >> 16))    * sp[2*k+1];
    ow[k] = (uint32_t)f2b(v0 * scale) | ((uint32_t)f2b(v1 * scale) << 16);
  }
#pragma unroll
  for (int k = 0; k < 4; ++k){
    float v0 = b2f((u16)(xs2[k] & 0xffff)) * cp[8+2*k]   + sgn * b2f((u16)(ps2[k] & 0xffff)) * sp[8+2*k];
    float v1 = b2f((u16)(xs2[k] >> 16))    * cp[8+2*k+1] + sgn * b2f((u16)(ps2[k] >> 16))    * sp[8+2*k+1];
    ow[4+k] = (uint32_t)f2b(v0 * scale) | ((uint32_t)f2b(v1 * scale) << 16);
  }
  u16* dst;
  if (head < NQH) dst = Qo + (((size_t)(b * NQH + head) * S_LEN + s) << 6) + d0;
  else            dst = Ko + (((size_t)(b * NKH + head - NQH) * S_LEN + s) << 6) + d0;
  uint4 o0 = {ow[0], ow[1], ow[2], ow[3]};
  uint4 o1 = {ow[4], ow[5], ow[6], ow[7]};
  *(uint4*)dst = o0;
  *(uint4*)(dst + 8) = o1;
}

// ---------------- V transpose + k-permute: qkv v-heads -> VT[b][kh][d][t*128+k] ----------------
// VT[d][t*128+k] = V[s = t*128 + h(k)][d], h(k) = 32*(k>>5) + 16*((k>>2)&1)
// + 4*((k>>3)&3) + (k&3). Bijection is 32-block-local -> PV B-frag equals the
// lane's own P words (zero-shuffle PV), and survives kv-group splitting.
__global__ __launch_bounds__(256)
void vtrans(const u16* __restrict__ qkv, u16* __restrict__ VT)
{
  int bid = blockIdx.x;                 // (b*8+kh)*16 + t
  int t = bid & 15, kh = (bid >> 4) & 7, b = bid >> 7;
  __shared__ u16 vlds[128][72];
  int tid = threadIdx.x;
  {
    int r = tid >> 1, half = tid & 1;
    const u16* src = qkv + (((size_t)(b * S_LEN + t * 128 + r) * 48 + 40 + kh) << 6) + half * 32;
    uint4 a0 = *(const uint4*)(src);
    uint4 a1 = *(const uint4*)(src + 8);
    uint4 a2 = *(const uint4*)(src + 16);
    uint4 a3 = *(const uint4*)(src + 24);
    *(uint4*)&vlds[r][half * 32]      = a0;
    *(uint4*)&vlds[r][half * 32 + 8]  = a1;
    *(uint4*)&vlds[r][half * 32 + 16] = a2;
    *(uint4*)&vlds[r][half * 32 + 24] = a3;
  }
  __syncthreads();
  const int d = tid >> 2, kk2 = tid & 3;
  u16* dst = VT + ((size_t)(b * NKH + kh) * 64 + d) * S_LEN + t * 128 + kk2 * 32;
#pragma unroll
  for (int j = 0; j < 4; ++j){          // j = lg
    u16 o[8];
#pragma unroll
    for (int e = 0; e < 8; ++e){
      const int hk = kk2 * 32 + ((e >> 2) << 4) + j * 4 + (e & 3);
      o[e] = vlds[hk][d];
    }
    uint4 ov = { (uint32_t)o[0] | ((uint32_t)o[1] << 16), (uint32_t)o[2] | ((uint32_t)o[3] << 16),
                 (uint32_t)o[4] | ((uint32_t)o[5] << 16), (uint32_t)o[6] | ((uint32_t)o[7] << 16) };
    *(uint4*)(dst + j * 8) = ov;
  }
}

// ---------------- attention helper: softmax + pack over a 64-kv half ----------------
// sv[nj][jj] = S^T[kv = kvbase + nj*16+lg*4+jj][q = w*16+lc] (exp2 domain).
// pw[k2][0..3] = PV B-frag words for LOCAL slice k2 (global kk2 = 2*kvg + k2).
__device__ __forceinline__ void proc_chunk4(f32x4 (&sv)[4], float& mrow, float& lsum,
                                            f32x4 (&o)[4], uint32_t (&pw)[2][4],
                                            const int lg, const int lc,
                                            const bool diag, const int qloc, const int kvbase)
{
  if (diag){
#pragma unroll
    for (int nj = 0; nj < 4; ++nj)
#pragma unroll
      for (int jj = 0; jj < 4; ++jj){
        const int kloc = kvbase + nj * 16 + lg * 4 + jj;
        if (kloc > qloc) sv[nj][jj] = MNEG;
      }
  }
  float mu = sv[0][0];
#pragma unroll
  for (int nj = 0; nj < 4; ++nj)
#pragma unroll
    for (int jj = 0; jj < 4; ++jj) mu = fmaxf(mu, sv[nj][jj]);
  mu = fmaxf(mu, __shfl_xor(mu, 16));
  mu = fmaxf(mu, __shfl_xor(mu, 32));
  // defer-max (log2 domain): skip rescale unless max grew past THR
  if (!__all(mu <= mrow + 11.54f)){
    const float mnew = fmaxf(mrow, mu);
    const float sf = __builtin_amdgcn_exp2f(mrow - mnew);
    mrow = mnew;
    lsum *= sf;
#pragma unroll
    for (int dn = 0; dn < 4; ++dn)
#pragma unroll
      for (int jj = 0; jj < 4; ++jj) o[dn][jj] *= sf;
  }
  const float mcur = mrow;
  float ps = 0.f;
#pragma unroll
  for (int nj = 0; nj < 4; ++nj)
#pragma unroll
    for (int jj = 0; jj < 4; ++jj){
      const float pv = __builtin_amdgcn_exp2f(sv[nj][jj] - mcur);
      sv[nj][jj] = pv;
      ps += pv;
    }
  lsum += ps;                          // per-lane partial (reduced in epilogue)
#pragma unroll
  for (int k2 = 0; k2 < 2; ++k2){
    pw[k2][0] = cvt_pk_bf16(sv[k2 * 2][0],     sv[k2 * 2][1]);
    pw[k2][1] = cvt_pk_bf16(sv[k2 * 2][2],     sv[k2 * 2][3]);
    pw[k2][2] = cvt_pk_bf16(sv[k2 * 2 + 1][0], sv[k2 * 2 + 1][1]);
    pw[k2][3] = cvt_pk_bf16(sv[k2 * 2 + 1][2], sv[k2 * 2 + 1][3]);
  }
}

__device__ __forceinline__ short8 pw_frag(const uint32_t* pw){
  u32x4 v = { pw[0], pw[1], pw[2], pw[3] };
  return __builtin_bit_cast(short8, v);
}

// ---------------- causal GQA flash attention, kv-split wave groups ----------------
// Block = 1 head, complement chunk pair (qt0=p, qt1=31-p), BKV=128 dbuf,
// 512 threads / 8 waves: waves 0-3 (kvg=0) process kv[0:64) of each tile,
// waves 4-7 (kvg=1) kv[64:128). Each wave reads HALF the K/V tile per iter
// (LDS-BW bound halved, R11 diagnosis). Independent online-softmax state per
// group, merged once in the epilogue (flash merge via LDS). Zero-shuffle PV
// (k-permuted V, 32-block-local). Diagonal tile: a group with no visible kv
// (kvg=1, qt even) SKIPS the chunk (guards exp2(MNEG-MNEG)=1 corruption).
__global__ __launch_bounds__(512, 2)
void attn_kernel(const u16* __restrict__ Q, const u16* __restrict__ Kr,
                 const u16* __restrict__ VT, u16* __restrict__ Ao)
{
  int bid = blockIdx.x;
  int p  = bid & 15;
  int g  = (bid >> 4) & 3;
  int kh = (bid >> 6) & 7;
  int b  = bid >> 9;
  const int h = kh * 4 + g;
  const int qt0 = p, qt1 = 31 - p;     // chunk tile indices (64-row units)

  __shared__ alignas(16) u16 smem[32768];        // 64KB: lK[2][128*64] | lV[2][64*128]
  char* lKb = (char*)smem;                       // +cur*16384
  char* lVb = (char*)smem + 32768;               // +cur*16384

  const int tid = threadIdx.x;
  const int kvg = tid >> 8;            // kv group (0: kv 0-63, 1: kv 64-127)
  const int w   = (tid >> 6) & 3;      // q sub-tile wave
  const int l   = tid & 63;
  const int lg = l >> 4, lc = l & 15;
  const int kvbase = kvg * 64;

  // Q fragments (B-operand layout): q = qt*64 + w*16 + lc, d = kk*32 + lg*8
  short8 qf[2][2];
  {
    const u16* qbase = Q + ((size_t)(b * NQH + h) * S_LEN) * 64;
#pragma unroll
    for (int kk = 0; kk < 2; ++kk){
      qf[0][kk] = *(const short8*)(qbase + (size_t)(qt0 * 64 + w * 16 + lc) * 64 + kk * 32 + lg * 8);
      qf[1][kk] = *(const short8*)(qbase + (size_t)(qt1 * 64 + w * 16 + lc) * 64 + kk * 32 + lg * 8);
    }
  }

  const u16* Kb = Kr + (size_t)(b * NKH + kh) * S_LEN * 64;
  const u16* Vb = VT + (size_t)(b * NKH + kh) * 64 * S_LEN;

  f32x4 o[2][4] = {};                  // O^T frag per chunk (this group's kv subset)
  float mrow[2] = {MNEG, MNEG};
  float lsum[2] = {0.f, 0.f};

  const int nt  = (qt1 >> 1) + 1;      // 128-kv units
  const int nt0 = qt0 >> 1;
  const int td0 = qt0 >> 1, td1 = qt1 >> 1;
  const bool odd0 = (qt0 & 1) != 0, odd1 = (qt1 & 1) != 0;

#define STAGE(T, BSEL) do { \
    _Pragma("unroll") \
    for (int i_ = 0; i_ < 2; ++i_){ \
      const int row_ = i_ * 64 + (tid >> 3); \
      const int ch_  = tid & 7; \
      const int gc_  = ((ch_ ^ (row_ & 7)) << 4); \
      gload_lds16((const char*)(Kb + (size_t)((T) * 128 + row_) * 64) + gc_, \
                  lKb + (BSEL) * 16384 + row_ * 128 + ch_ * 16); \
    } \
    _Pragma("unroll") \
    for (int i_ = 0; i_ < 2; ++i_){ \
      const int row_ = i_ * 32 + (tid >> 4); \
      const int ch_  = tid & 15; \
      const int gc_  = ((ch_ ^ (row_ & 15)) << 4); \
      gload_lds16((const char*)(Vb + (size_t)row_ * S_LEN + (T) * 128) + gc_, \
                  lVb + (BSEL) * 16384 + row_ * 256 + ch_ * 16); \
    } \
  } while (0)

  STAGE(0, 0);

  for (int t = 0; t < nt; ++t){
    const int cur = t & 1;
    // chunk activity for THIS kv group (skip fully-masked diagonal halves)
    const bool a0 = (t <= nt0) && !(kvg == 1 && t == td0 && !odd0);
    const bool a1 = !(kvg == 1 && t == td1 && !odd1);
    if (t + 1 < nt){
      STAGE(t + 1, cur ^ 1);
      asm volatile("s_waitcnt vmcnt(4)" ::: "memory");   // tile-t loads landed
    } else {
      asm volatile("s_waitcnt vmcnt(0)" ::: "memory");
    }
    __builtin_amdgcn_s_barrier();

    // S^T = K Q^T over this group's kv half
    f32x4 sv[2][4] = {};
    __builtin_amdgcn_s_setprio(1);
#pragma unroll
    for (int kk = 0; kk < 2; ++kk){
      short8 kf[4];
#pragma unroll
      for (int nj = 0; nj < 4; ++nj){
        const int row = kvbase + nj * 16 + lc;
        const int cc = (kk * 4 + lg) ^ (row & 7);
        kf[nj] = *(const short8*)(lKb + cur * 16384 + row * 128 + cc * 16);
      }
      if (a0)
#pragma unroll
        for (int nj = 0; nj < 4; ++nj)
          sv[0][nj] = __builtin_amdgcn_mfma_f32_16x16x32_bf16(kf[nj], qf[0][kk], sv[0][nj], 0, 0, 0);
      if (a1)
#pragma unroll
        for (int nj = 0; nj < 4; ++nj)
          sv[1][nj] = __builtin_amdgcn_mfma_f32_16x16x32_bf16(kf[nj], qf[1][kk], sv[1][nj], 0, 0, 0);
    }
    __builtin_amdgcn_s_setprio(0);

    uint32_t pw[2][2][4];
    if (a0)
      proc_chunk4(sv[0], mrow[0], lsum[0], o[0], pw[0], lg, lc,
                  t == td0, (qt0 & 1) * 64 + w * 16 + lc, kvbase);
    if (a1)
      proc_chunk4(sv[1], mrow[1], lsum[1], o[1], pw[1], lg, lc,
                  t == td1, (qt1 & 1) * 64 + w * 16 + lc, kvbase);

    // O^T += V^T P^T over this group's kv half (global kk2 = 2*kvg + k2)
    __builtin_amdgcn_s_setprio(1);
#pragma unroll
    for (int k2 = 0; k2 < 2; ++k2){
      const int kk2g = kvg * 2 + k2;
      short8 vf[4];
#pragma unroll
      for (int dn = 0; dn < 4; ++dn){
        const int row = dn * 16 + lc;
        const int cc = (kk2g * 4 + lg) ^ (row & 15);
        vf[dn] = *(const short8*)(lVb + cur * 16384 + row * 256 + cc * 16);
      }
      if (a0){
        const short8 pb0 = pw_frag(pw[0][k2]);
#pragma unroll
        for (int dn = 0; dn < 4; ++dn)
          o[0][dn] = __builtin_amdgcn_mfma_f32_16x16x32_bf16(vf[dn], pb0, o[0][dn], 0, 0, 0);
      }
      if (a1){
        const short8 pb1 = pw_frag(pw[1][k2]);
#pragma unroll
        for (int dn = 0; dn < 4; ++dn)
          o[1][dn] = __builtin_amdgcn_mfma_f32_16x16x32_bf16(vf[dn], pb1, o[1][dn], 0, 0, 0);
      }
    }
    __builtin_amdgcn_s_setprio(0);
    __builtin_amdgcn_s_barrier();
  }
#undef STAGE

  // ---- epilogue: reduce lsum, merge kv groups (flash merge), write out ----
  float ls[2];
#pragma unroll
  for (int c = 0; c < 2; ++c){
    float v = lsum[c];
    v += __shfl_xor(v, 16);
    v += __shfl_xor(v, 32);
    ls[c] = v;
  }
  __syncthreads();                     // all tile reads done; smem reusable
  float* mb = (float*)smem;            // [wave(4)][chunk(2)][lane(64)][20]
  if (kvg == 1){
#pragma unroll
    for (int c = 0; c < 2; ++c){
      float* base = mb + (((w * 2 + c) * 64) + l) * 20;
#pragma unroll
      for (int dn = 0; dn < 4; ++dn)
        *(f32x4*)(base + dn * 4) = o[c][dn];
      base[16] = mrow[c];
      base[17] = ls[c];
    }
  }
  __syncthreads();
  if (kvg == 0){
#pragma unroll
    for (int c = 0; c < 2; ++c){
      const int qt = c ? qt1 : qt0;
      float* base = mb + (((w * 2 + c) * 64) + l) * 20;
      const float mB = base[16];
      const float lB = base[17];
      const float m  = fmaxf(mrow[c], mB);
      const float wA = __builtin_amdgcn_exp2f(mrow[c] - m);
      const float wB = __builtin_amdgcn_exp2f(mB - m);
      const float inv = 1.f / (ls[c] * wA + lB * wB);
      const int sq = qt * 64 + w * 16 + lc;
#pragma unroll
      for (int dn = 0; dn < 4; ++dn){
        f32x4 ob = *(const f32x4*)(base + dn * 4);
        float v0 = (o[c][dn][0] * wA + ob[0] * wB) * inv;
        float v1 = (o[c][dn][1] * wA + ob[1] * wB) * inv;
        float v2 = (o[c][dn][2] * wA + ob[2] * wB) * inv;
        float v3 = (o[c][dn][3] * wA + ob[3] * wB) * inv;
        uint2 pk;
        pk.x = cvt_pk_bf16(v0, v1);
        pk.y = cvt_pk_bf16(v2, v3);
        const int col = h * 64 + dn * 16 + lg * 4;
        *(uint2*)&Ao[(size_t)(b * S_LEN + sq) * 2048 + col] = pk;
      }
    }
  }
}

// ---------------- launcher ----------------
extern "C" void kernel_launch(void* const* d_in, const int* in_sizes, int n_in,
                              void* d_out, int out_size, void* d_ws, size_t ws_size,
                              hipStream_t stream)
{
  const float* cosT = (const float*)d_in[0];
  const float* sinT = (const float*)d_in[1];
  const float* hs   = (const float*)d_in[2];
  const float* phs  = (const float*)d_in[3];
  const float* Wqkv = (const float*)d_in[4];
  const float* Wo   = (const float*)d_in[5];
  float* out = (float*)d_out;
  char* ws = (char*)d_ws;

  u16* hsB   = (u16*)(ws);               // 16,777,216 B (aliased as attn_out later)
  u16* WqkvB = (u16*)(ws + 16777216);    // 12,582,912 B
  u16* WoB   = (u16*)(ws + 29360128);    //  8,388,608 B
  u16* qkvB  = (u16*)(ws + 37748736);    // 25,165,824 B
  u16* Qb    = (u16*)(ws + 62914560);    // 16,777,216 B
  u16* Kb    = (u16*)(ws + 79691776);    //  4,194,304 B
  u16* VTb   = (u16*)(ws + 83886080);    //  4,194,304 B  (total 88,080,384 B)
  u16* Ao    = hsB;                      // hsB dead after GEMM1

  cvt_all<<<18432, 256, 0, stream>>>(hs, Wqkv, Wo, hsB, WqkvB, WoB);
  gemm_bt<0><<<dim3(24, 32), 256, 0, stream>>>(hsB, WqkvB, (void*)qkvB, 3072, 2048);
  rope_kernel<<<2560, 256, 0, stream>>>(qkvB, cosT, sinT, phs, Qb, Kb);
  vtrans<<<256, 256, 0, stream>>>(qkvB, VTb);
  attn_kernel<<<1024, 512, 0, stream>>>(Qb, Kb, VTb, Ao);
  gemm_bt<1><<<dim3(16, 32), 256, 0, stream>>>(Ao, WoB, (void*)out, 2048, 2048);
}

// Round 13
// 224.780 us; speedup vs baseline: 1.0478x; 1.0478x over previous
//
#include <hip/hip_runtime.h>
#include <stdint.h>

typedef unsigned short u16;
typedef short short8 __attribute__((ext_vector_type(8)));
typedef float f32x4 __attribute__((ext_vector_type(4)));
typedef uint32_t u32x4 __attribute__((ext_vector_type(4)));

#define S_LEN 2048
#define NQH 32
#define NKH 8
#define DHD 64
#define MNEG -1.0e30f

__device__ __forceinline__ float b2f(u16 u){
  union { uint32_t i; float f; } c; c.i = ((uint32_t)u) << 16; return c.f;
}
__device__ __forceinline__ u16 f2b(float f){
  union { float f; uint32_t i; } c; c.f = f;
  uint32_t r = c.i + 0x7fffu + ((c.i >> 16) & 1u);
  return (u16)(r >> 16);
}
__device__ __forceinline__ uint32_t cvt_pk_bf16(float lo, float hi){
  uint32_t r;
  asm("v_cvt_pk_bf16_f32 %0, %1, %2" : "=v"(r) : "v"(lo), "v"(hi));
  return r;
}
__device__ __forceinline__ void gload_lds16(const void* g, void* l){
  __builtin_amdgcn_global_load_lds((const __attribute__((address_space(1))) uint32_t*)g,
                                   (__attribute__((address_space(3))) uint32_t*)l, 16, 0, 0);
}

// ------- fused fp32 -> bf16 convert (hs | Wqkv | Wo) + cos/sin bf16 pack -------
__global__ __launch_bounds__(256) void cvt_all(const float* __restrict__ hs,
                                               const float* __restrict__ wq,
                                               const float* __restrict__ wo,
                                               const float* __restrict__ cosp,
                                               const float* __restrict__ sinp,
                                               u16* __restrict__ hsB,
                                               u16* __restrict__ wqB,
                                               u16* __restrict__ woB,
                                               uint32_t* __restrict__ csB){
  int i = blockIdx.x * 256 + threadIdx.x;       // 4718592 f32x4 + 32768 cs-x4
  if (i >= 4718592){
    int off = i - 4718592;                      // 0..32767
    float4 c = ((const float4*)cosp)[off];
    float4 s = ((const float4*)sinp)[off];
    u32x4 o = { (uint32_t)f2b(c.x) | ((uint32_t)f2b(s.x) << 16),
                (uint32_t)f2b(c.y) | ((uint32_t)f2b(s.y) << 16),
                (uint32_t)f2b(c.z) | ((uint32_t)f2b(s.z) << 16),
                (uint32_t)f2b(c.w) | ((uint32_t)f2b(s.w) << 16) };
    ((u32x4*)csB)[off] = o;
    return;
  }
  const float* src; u16* dst; int off;
  if (i < 2097152)      { src = hs; dst = hsB; off = i; }
  else if (i < 3670016) { src = wq; dst = wqB; off = i - 2097152; }
  else                  { src = wo; dst = woB; off = i - 3670016; }
  float4 v = ((const float4*)src)[off];
  uint2 o;
  o.x = (uint32_t)f2b(v.x) | ((uint32_t)f2b(v.y) << 16);
  o.y = (uint32_t)f2b(v.z) | ((uint32_t)f2b(v.w) << 16);
  ((uint2*)dst)[off] = o;
}

// ---------------- bf16 GEMM: C[M][N] = A[M][K] * B[N][K]^T (generic, f32 out) ----------------
template<int OUT_F32>
__global__ __launch_bounds__(256)
void gemm_bt(const u16* __restrict__ A, const u16* __restrict__ Bm,
             void* __restrict__ Cp, int N, int K)
{
  __shared__ alignas(16) u16 lA[128 * 64];
  __shared__ alignas(16) u16 lB[128 * 64];
  const int tid = threadIdx.x;
  const int w = tid >> 6, l = tid & 63;
  const int lg = l >> 4, lc = l & 15;
  const int wm = w >> 1, wn = w & 1;
  const int m0 = blockIdx.y * 128, n0 = blockIdx.x * 128;
  const int srow = l >> 3, sc = l & 7;
  const size_t ldb = (size_t)K * 2;   // row bytes
  f32x4 acc[4][4] = {};
  const int kiters = K >> 6;
  for (int kt = 0; kt < kiters; ++kt){
    __syncthreads();
#pragma unroll
    for (int i = 0; i < 4; ++i){
      const int row = (i * 4 + w) * 8 + srow;
      const int gc = ((sc ^ (row & 7)) << 4);
      gload_lds16((const char*)A + (size_t)(m0 + row) * ldb + (size_t)kt * 128 + gc,
                  (char*)lA + row * 128 + sc * 16);
    }
#pragma unroll
    for (int i = 0; i < 4; ++i){
      const int row = (i * 4 + w) * 8 + srow;
      const int gc = ((sc ^ (row & 7)) << 4);
      gload_lds16((const char*)Bm + (size_t)(n0 + row) * ldb + (size_t)kt * 128 + gc,
                  (char*)lB + row * 128 + sc * 16);
    }
    __syncthreads();
#pragma unroll
    for (int kk = 0; kk < 2; ++kk){
      short8 af[4], bfr[4];
#pragma unroll
      for (int mi = 0; mi < 4; ++mi){
        const int row = wm * 64 + mi * 16 + lc;
        const int cc = (kk * 4 + lg) ^ (row & 7);
        af[mi] = *(const short8*)((const char*)lA + row * 128 + cc * 16);
      }
#pragma unroll
      for (int ni = 0; ni < 4; ++ni){
        const int row = wn * 64 + ni * 16 + lc;
        const int cc = (kk * 4 + lg) ^ (row & 7);
        bfr[ni] = *(const short8*)((const char*)lB + row * 128 + cc * 16);
      }
#pragma unroll
      for (int mi = 0; mi < 4; ++mi)
#pragma unroll
        for (int ni = 0; ni < 4; ++ni)
          acc[mi][ni] = __builtin_amdgcn_mfma_f32_16x16x32_bf16(af[mi], bfr[ni], acc[mi][ni], 0, 0, 0);
    }
  }
  const int r0 = m0 + wm * 64 + lg * 4;
  const int c0 = n0 + wn * 64 + lc;
#pragma unroll
  for (int mi = 0; mi < 4; ++mi)
#pragma unroll
    for (int ni = 0; ni < 4; ++ni)
#pragma unroll
      for (int j = 0; j < 4; ++j){
        const size_t idx = (size_t)(r0 + mi * 16 + j) * (size_t)N + (size_t)(c0 + ni * 16);
        if (OUT_F32) ((float*)Cp)[idx] = acc[mi][ni][j];
        else         ((u16*)Cp)[idx]  = f2b(acc[mi][ni][j]);
      }
}

// ---------------- GEMM1 + fused RoPE/scale epilogue ----------------
// qkv = hs * Wqkv^T (M=4096, N=3072, K=2048). Per thread the epilogue owns one
// head and 4 d-positions {lc+16ni}; the RoPE partner d^32 is acc[mi][ni^2][j]
// (same thread). Q: rotate * 1.2*kscale*phs -> Qb[b][h][s][64]; K: rotate*1.2
// -> Kb[b][kh][s][64]; V: raw -> Vraw[b][s][8][64]. cos/sin from packed bf16
// table csB[s][d] (cos lo, sin hi).
__global__ __launch_bounds__(256)
void gemm1_rope(const u16* __restrict__ A, const u16* __restrict__ Bm,
                const uint32_t* __restrict__ cs, const float* __restrict__ phs,
                u16* __restrict__ Qo, u16* __restrict__ Ko, u16* __restrict__ Vraw)
{
  __shared__ alignas(16) u16 lA[128 * 64];
  __shared__ alignas(16) u16 lB[128 * 64];
  const int tid = threadIdx.x;
  const int w = tid >> 6, l = tid & 63;
  const int lg = l >> 4, lc = l & 15;
  const int wm = w >> 1, wn = w & 1;
  const int m0 = blockIdx.y * 128, n0 = blockIdx.x * 128;
  const int srow = l >> 3, sc = l & 7;
  const size_t ldb = 4096;            // K=2048 row bytes
  f32x4 acc[4][4] = {};
  for (int kt = 0; kt < 32; ++kt){
    __syncthreads();
#pragma unroll
    for (int i = 0; i < 4; ++i){
      const int row = (i * 4 + w) * 8 + srow;
      const int gc = ((sc ^ (row & 7)) << 4);
      gload_lds16((const char*)A + (size_t)(m0 + row) * ldb + (size_t)kt * 128 + gc,
                  (char*)lA + row * 128 + sc * 16);
    }
#pragma unroll
    for (int i = 0; i < 4; ++i){
      const int row = (i * 4 + w) * 8 + srow;
      const int gc = ((sc ^ (row & 7)) << 4);
      gload_lds16((const char*)Bm + (size_t)(n0 + row) * ldb + (size_t)kt * 128 + gc,
                  (char*)lB + row * 128 + sc * 16);
    }
    __syncthreads();
#pragma unroll
    for (int kk = 0; kk < 2; ++kk){
      short8 af[4], bfr[4];
#pragma unroll
      for (int mi = 0; mi < 4; ++mi){
        const int row = wm * 64 + mi * 16 + lc;
        const int cc = (kk * 4 + lg) ^ (row & 7);
        af[mi] = *(const short8*)((const char*)lA + row * 128 + cc * 16);
      }
#pragma unroll
      for (int ni = 0; ni < 4; ++ni){
        const int row = wn * 64 + ni * 16 + lc;
        const int cc = (kk * 4 + lg) ^ (row & 7);
        bfr[ni] = *(const short8*)((const char*)lB + row * 128 + cc * 16);
      }
#pragma unroll
      for (int mi = 0; mi < 4; ++mi)
#pragma unroll
        for (int ni = 0; ni < 4; ++ni)
          acc[mi][ni] = __builtin_amdgcn_mfma_f32_16x16x32_bf16(af[mi], bfr[ni], acc[mi][ni], 0, 0, 0);
    }
  }
  const int r0 = m0 + wm * 64 + lg * 4;
  const int c0 = n0 + wn * 64 + lc;
  const int head = (n0 + wn * 64) >> 6;          // one head per thread
  const int b = m0 >> 11;
  if (head < 40){
    const float scale = (head < NQH) ? 1.2f * 0.18033688011112042f * phs[b * NQH + head] : 1.2f;
    u16* dstbase = (head < NQH)
        ? (Qo + ((size_t)(b * NQH + head) * S_LEN) * 64)
        : (Ko + ((size_t)(b * NKH + (head - NQH)) * S_LEN) * 64);
#pragma unroll
    for (int mi = 0; mi < 4; ++mi)
#pragma unroll
      for (int j = 0; j < 4; ++j){
        const int s = (r0 + mi * 16 + j) & 2047;
        const uint32_t* csrow = cs + s * 64;
        float xs[4] = {acc[mi][0][j], acc[mi][1][j], acc[mi][2][j], acc[mi][3][j]};
#pragma unroll
        for (int ni = 0; ni < 4; ++ni){
          const int d = lc + ni * 16;
          const uint32_t csv = csrow[d];
          const float cv = b2f((u16)(csv & 0xffff));
          const float sv = b2f((u16)(csv >> 16));
          const float sgn = (ni < 2) ? -1.f : 1.f;
          const float v = (xs[ni] * cv + sgn * xs[ni ^ 2] * sv) * scale;
          dstbase[(size_t)s * 64 + d] = f2b(v);
        }
      }
  } else {
    // V heads -> compact Vraw[b][s][8][64]
#pragma unroll
    for (int mi = 0; mi < 4; ++mi)
#pragma unroll
      for (int ni = 0; ni < 4; ++ni)
#pragma unroll
        for (int j = 0; j < 4; ++j){
          const int r = r0 + mi * 16 + j;
          Vraw[(size_t)r * 512 + (c0 + ni * 16 - 2560)] = f2b(acc[mi][ni][j]);
        }
  }
}

// ---------------- V transpose + k-permute: Vraw[b][s][8][64] -> VT[b][kh][d][t*128+k] ----------------
// VT[d][t*128+k] = V[s = t*128 + h(k)][d], h(k) = 32*(k>>5) + 16*((k>>2)&1)
// + 4*((k>>3)&3) + (k&3). Bijection is 32-block-local -> PV B-frag equals the
// lane's own P words (zero-shuffle PV).
__global__ __launch_bounds__(256)
void vtrans(const u16* __restrict__ Vraw, u16* __restrict__ VT)
{
  int bid = blockIdx.x;                 // (b*8+kh)*16 + t
  int t = bid & 15, kh = (bid >> 4) & 7, b = bid >> 7;
  __shared__ u16 vlds[128][72];
  int tid = threadIdx.x;
  {
    int r = tid >> 1, half = tid & 1;
    const u16* src = Vraw + (((size_t)(b * S_LEN + t * 128 + r) * 8 + kh) << 6) + half * 32;
    uint4 a0 = *(const uint4*)(src);
    uint4 a1 = *(const uint4*)(src + 8);
    uint4 a2 = *(const uint4*)(src + 16);
    uint4 a3 = *(const uint4*)(src + 24);
    *(uint4*)&vlds[r][half * 32]      = a0;
    *(uint4*)&vlds[r][half * 32 + 8]  = a1;
    *(uint4*)&vlds[r][half * 32 + 16] = a2;
    *(uint4*)&vlds[r][half * 32 + 24] = a3;
  }
  __syncthreads();
  const int d = tid >> 2, kk2 = tid & 3;
  u16* dst = VT + ((size_t)(b * NKH + kh) * 64 + d) * S_LEN + t * 128 + kk2 * 32;
#pragma unroll
  for (int j = 0; j < 4; ++j){          // j = lg
    u16 o[8];
#pragma unroll
    for (int e = 0; e < 8; ++e){
      const int hk = kk2 * 32 + ((e >> 2) << 4) + j * 4 + (e & 3);
      o[e] = vlds[hk][d];
    }
    uint4 ov = { (uint32_t)o[0] | ((uint32_t)o[1] << 16), (uint32_t)o[2] | ((uint32_t)o[3] << 16),
                 (uint32_t)o[4] | ((uint32_t)o[5] << 16), (uint32_t)o[6] | ((uint32_t)o[7] << 16) };
    *(uint4*)(dst + j * 8) = ov;
  }
}

// ---------------- attention helper: softmax + pack (zero-shuffle PV) ----------------
// Verified R11. sv[nj][jj] = S^T[kv = nj*16+lg*4+jj][q = w*16+lc] (exp2 domain).
__device__ __forceinline__ void proc_chunk(f32x4 (&sv)[8], float& mrow, float& lsum,
                                           f32x4 (&o)[4], uint32_t (&pw)[4][4],
                                           const int lg, const int lc,
                                           const bool diag, const int qloc)
{
  if (diag){
#pragma unroll
    for (int nj = 0; nj < 8; ++nj)
#pragma unroll
      for (int jj = 0; jj < 4; ++jj){
        const int kloc = nj * 16 + lg * 4 + jj;
        if (kloc > qloc) sv[nj][jj] = MNEG;
      }
  }
  float mu = sv[0][0];
#pragma unroll
  for (int nj = 0; nj < 8; ++nj)
#pragma unroll
    for (int jj = 0; jj < 4; ++jj) mu = fmaxf(mu, sv[nj][jj]);
  mu = fmaxf(mu, __shfl_xor(mu, 16));
  mu = fmaxf(mu, __shfl_xor(mu, 32));
  if (!__all(mu <= mrow + 11.54f)){
    const float mnew = fmaxf(mrow, mu);
    const float sf = __builtin_amdgcn_exp2f(mrow - mnew);
    mrow = mnew;
    lsum *= sf;
#pragma unroll
    for (int dn = 0; dn < 4; ++dn)
#pragma unroll
      for (int jj = 0; jj < 4; ++jj) o[dn][jj] *= sf;
  }
  const float mcur = mrow;
  float ps = 0.f;
#pragma unroll
  for (int nj = 0; nj < 8; ++nj)
#pragma unroll
    for (int jj = 0; jj < 4; ++jj){
      const float pv = __builtin_amdgcn_exp2f(sv[nj][jj] - mcur);
      sv[nj][jj] = pv;
      ps += pv;
    }
  lsum += ps;                          // per-lane partial (reduced in epilogue)
#pragma unroll
  for (int kk2 = 0; kk2 < 4; ++kk2){
    pw[kk2][0] = cvt_pk_bf16(sv[kk2 * 2][0],     sv[kk2 * 2][1]);
    pw[kk2][1] = cvt_pk_bf16(sv[kk2 * 2][2],     sv[kk2 * 2][3]);
    pw[kk2][2] = cvt_pk_bf16(sv[kk2 * 2 + 1][0], sv[kk2 * 2 + 1][1]);
    pw[kk2][3] = cvt_pk_bf16(sv[kk2 * 2 + 1][2], sv[kk2 * 2 + 1][3]);
  }
}

__device__ __forceinline__ short8 pw_frag(const uint32_t* pw){
  u32x4 v = { pw[0], pw[1], pw[2], pw[3] };
  return __builtin_bit_cast(short8, v);
}

// ---------------- causal GQA flash attention (R11-verified) ----------------
// 512 threads / 8 waves: waves 0-3 head h0, waves 4-7 head h0+1, shared 64KB
// K/V double-buffer (BKV=128, counted vmcnt). Swapped QK^T, in-lane softmax,
// defer-max, zero-shuffle PV via k-permuted V tile (see vtrans).
__global__ __launch_bounds__(512, 2)
void attn_kernel(const u16* __restrict__ Q, const u16* __restrict__ Kr,
                 const u16* __restrict__ VT, u16* __restrict__ Ao)
{
  int bid = blockIdx.x;
  int p  = bid & 15;
  int gp = (bid >> 4) & 1;
  int kh = (bid >> 5) & 7;
  int b  = bid >> 8;
  const int qt0 = p, qt1 = 31 - p;     // chunk tile indices (64-row units)

  __shared__ alignas(16) u16 lK[2][128 * 64];    // [buf][kv j][d], swizzle ^(row&7)
  __shared__ alignas(16) u16 lV[2][64 * 128];    // [buf][d][k-permuted kv], swizzle ^(row&15)

  const int tid = threadIdx.x;
  const int hh = tid >> 8;             // head select (wave group)
  const int h  = kh * 4 + gp * 2 + hh;
  const int w  = (tid >> 6) & 3;       // wave within head group
  const int l  = tid & 63;
  const int lg = l >> 4, lc = l & 15;

  short8 qf[2][2];
  {
    const u16* qbase = Q + ((size_t)(b * NQH + h) * S_LEN) * 64;
#pragma unroll
    for (int kk = 0; kk < 2; ++kk){
      qf[0][kk] = *(const short8*)(qbase + (size_t)(qt0 * 64 + w * 16 + lc) * 64 + kk * 32 + lg * 8);
      qf[1][kk] = *(const short8*)(qbase + (size_t)(qt1 * 64 + w * 16 + lc) * 64 + kk * 32 + lg * 8);
    }
  }

  const u16* Kb = Kr + (size_t)(b * NKH + kh) * S_LEN * 64;
  const u16* Vb = VT + (size_t)(b * NKH + kh) * 64 * S_LEN;

  f32x4 o[2][4] = {};
  float mrow[2] = {MNEG, MNEG};
  float lsum[2] = {0.f, 0.f};

  const int nt = (qt1 >> 1) + 1;       // 128-kv units
  const int nt0 = qt0 >> 1;

#define STAGE(T, BSEL) do { \
    _Pragma("unroll") \
    for (int i_ = 0; i_ < 2; ++i_){ \
      const int row_ = i_ * 64 + (tid >> 3); \
      const int ch_  = tid & 7; \
      const int gc_  = ((ch_ ^ (row_ & 7)) << 4); \
      gload_lds16((const char*)(Kb + (size_t)((T) * 128 + row_) * 64) + gc_, \
                  (char*)lK[BSEL] + row_ * 128 + ch_ * 16); \
    } \
    _Pragma("unroll") \
    for (int i_ = 0; i_ < 2; ++i_){ \
      const int row_ = i_ * 32 + (tid >> 4); \
      const int ch_  = tid & 15; \
      const int gc_  = ((ch_ ^ (row_ & 15)) << 4); \
      gload_lds16((const char*)(Vb + (size_t)row_ * S_LEN + (T) * 128) + gc_, \
                  (char*)lV[BSEL] + row_ * 256 + ch_ * 16); \
    } \
  } while (0)

  STAGE(0, 0);

  for (int t = 0; t < nt; ++t){
    const int cur = t & 1;
    const bool act0 = (t <= nt0);
    if (t + 1 < nt){
      STAGE(t + 1, cur ^ 1);
      asm volatile("s_waitcnt vmcnt(4)" ::: "memory");
    } else {
      asm volatile("s_waitcnt vmcnt(0)" ::: "memory");
    }
    __builtin_amdgcn_s_barrier();

    f32x4 sv[2][8] = {};
    __builtin_amdgcn_s_setprio(1);
#pragma unroll
    for (int kk = 0; kk < 2; ++kk){
      short8 kf[8];
#pragma unroll
      for (int nj = 0; nj < 8; ++nj){
        const int row = nj * 16 + lc;
        const int cc = (kk * 4 + lg) ^ (row & 7);
        kf[nj] = *(const short8*)((const char*)lK[cur] + row * 128 + cc * 16);
      }
      if (act0)
#pragma unroll
        for (int nj = 0; nj < 8; ++nj)
          sv[0][nj] = __builtin_amdgcn_mfma_f32_16x16x32_bf16(kf[nj], qf[0][kk], sv[0][nj], 0, 0, 0);
#pragma unroll
      for (int nj = 0; nj < 8; ++nj)
        sv[1][nj] = __builtin_amdgcn_mfma_f32_16x16x32_bf16(kf[nj], qf[1][kk], sv[1][nj], 0, 0, 0);
    }
    __builtin_amdgcn_s_setprio(0);

    uint32_t pw[2][4][4];
    if (act0)
      proc_chunk(sv[0], mrow[0], lsum[0], o[0], pw[0], lg, lc,
                 t == (qt0 >> 1), (qt0 & 1) * 64 + w * 16 + lc);
    proc_chunk(sv[1], mrow[1], lsum[1], o[1], pw[1], lg, lc,
               t == (qt1 >> 1), (qt1 & 1) * 64 + w * 16 + lc);

    __builtin_amdgcn_s_setprio(1);
#pragma unroll
    for (int kk2 = 0; kk2 < 4; ++kk2){
      short8 vf[4];
#pragma unroll
      for (int dn = 0; dn < 4; ++dn){
        const int row = dn * 16 + lc;
        const int cc = (kk2 * 4 + lg) ^ (row & 15);
        vf[dn] = *(const short8*)((const char*)lV[cur] + row * 256 + cc * 16);
      }
      if (act0){
        const short8 pb0 = pw_frag(pw[0][kk2]);
#pragma unroll
        for (int dn = 0; dn < 4; ++dn)
          o[0][dn] = __builtin_amdgcn_mfma_f32_16x16x32_bf16(vf[dn], pb0, o[0][dn], 0, 0, 0);
      }
      const short8 pb1 = pw_frag(pw[1][kk2]);
#pragma unroll
      for (int dn = 0; dn < 4; ++dn)
        o[1][dn] = __builtin_amdgcn_mfma_f32_16x16x32_bf16(vf[dn], pb1, o[1][dn], 0, 0, 0);
    }
    __builtin_amdgcn_s_setprio(0);
    __builtin_amdgcn_s_barrier();
  }
#undef STAGE

#pragma unroll
  for (int c = 0; c < 2; ++c){
    const int qt = c ? qt1 : qt0;
    float ls = lsum[c];
    ls += __shfl_xor(ls, 16);
    ls += __shfl_xor(ls, 32);
    const float inv = 1.f / ls;
    const int sq = qt * 64 + w * 16 + lc;
#pragma unroll
    for (int dn = 0; dn < 4; ++dn){
      uint2 pk;
      pk.x = cvt_pk_bf16(o[c][dn][0] * inv, o[c][dn][1] * inv);
      pk.y = cvt_pk_bf16(o[c][dn][2] * inv, o[c][dn][3] * inv);
      const int col = h * 64 + dn * 16 + lg * 4;
      *(uint2*)&Ao[(size_t)(b * S_LEN + sq) * 2048 + col] = pk;
    }
  }
}

// ---------------- launcher ----------------
extern "C" void kernel_launch(void* const* d_in, const int* in_sizes, int n_in,
                              void* d_out, int out_size, void* d_ws, size_t ws_size,
                              hipStream_t stream)
{
  const float* cosT = (const float*)d_in[0];
  const float* sinT = (const float*)d_in[1];
  const float* hs   = (const float*)d_in[2];
  const float* phs  = (const float*)d_in[3];
  const float* Wqkv = (const float*)d_in[4];
  const float* Wo   = (const float*)d_in[5];
  float* out = (float*)d_out;
  char* ws = (char*)d_ws;

  u16* hsB   = (u16*)(ws);               // 16,777,216 B (aliased as attn_out later)
  u16* WqkvB = (u16*)(ws + 16777216);    // 12,582,912 B
  u16* WoB   = (u16*)(ws + 29360128);    //  8,388,608 B
  u16* Vraw  = (u16*)(ws + 37748736);    //  4,194,304 B
  u16* Qb    = (u16*)(ws + 41943040);    // 16,777,216 B
  u16* Kb    = (u16*)(ws + 58720256);    //  4,194,304 B
  u16* VTb   = (u16*)(ws + 62914560);    //  4,194,304 B
  uint32_t* csB = (uint32_t*)(ws + 67108864); // 524,288 B (total 67,633,152 B)
  u16* Ao    = hsB;                      // hsB dead after GEMM1

  cvt_all<<<18560, 256, 0, stream>>>(hs, Wqkv, Wo, cosT, sinT, hsB, WqkvB, WoB, csB);
  gemm1_rope<<<dim3(24, 32), 256, 0, stream>>>(hsB, WqkvB, csB, phs, Qb, Kb, Vraw);
  vtrans<<<256, 256, 0, stream>>>(Vraw, VTb);
  attn_kernel<<<512, 512, 0, stream>>>(Qb, Kb, VTb, Ao);
  gemm_bt<1><<<dim3(16, 32), 256, 0, stream>>>(Ao, WoB, (void*)out, 2048, 2048);
}

// Round 14
// 215.370 us; speedup vs baseline: 1.0936x; 1.0437x over previous
//
#include <hip/hip_runtime.h>
#include <stdint.h>

typedef unsigned short u16;
typedef short short8 __attribute__((ext_vector_type(8)));
typedef float f32x4 __attribute__((ext_vector_type(4)));
typedef uint32_t u32x4 __attribute__((ext_vector_type(4)));

#define S_LEN 2048
#define NQH 32
#define NKH 8
#define DHD 64
#define MNEG -1.0e30f

__device__ __forceinline__ float b2f(u16 u){
  union { uint32_t i; float f; } c; c.i = ((uint32_t)u) << 16; return c.f;
}
__device__ __forceinline__ u16 f2b(float f){
  union { float f; uint32_t i; } c; c.f = f;
  uint32_t r = c.i + 0x7fffu + ((c.i >> 16) & 1u);
  return (u16)(r >> 16);
}
__device__ __forceinline__ uint32_t cvt_pk_bf16(float lo, float hi){
  uint32_t r;
  asm("v_cvt_pk_bf16_f32 %0, %1, %2" : "=v"(r) : "v"(lo), "v"(hi));
  return r;
}
__device__ __forceinline__ void gload_lds16(const void* g, void* l){
  __builtin_amdgcn_global_load_lds((const __attribute__((address_space(1))) uint32_t*)g,
                                   (__attribute__((address_space(3))) uint32_t*)l, 16, 0, 0);
}

// ------- fused fp32 -> bf16 convert (hs | Wqkv | Wo) + cos/sin bf16 pack -------
__global__ __launch_bounds__(256) void cvt_all(const float* __restrict__ hs,
                                               const float* __restrict__ wq,
                                               const float* __restrict__ wo,
                                               const float* __restrict__ cosp,
                                               const float* __restrict__ sinp,
                                               u16* __restrict__ hsB,
                                               u16* __restrict__ wqB,
                                               u16* __restrict__ woB,
                                               uint32_t* __restrict__ csB){
  int i = blockIdx.x * 256 + threadIdx.x;       // 4718592 f32x4 + 32768 cs-x4
  if (i >= 4718592){
    int off = i - 4718592;                      // 0..32767
    float4 c = ((const float4*)cosp)[off];
    float4 s = ((const float4*)sinp)[off];
    u32x4 o = { (uint32_t)f2b(c.x) | ((uint32_t)f2b(s.x) << 16),
                (uint32_t)f2b(c.y) | ((uint32_t)f2b(s.y) << 16),
                (uint32_t)f2b(c.z) | ((uint32_t)f2b(s.z) << 16),
                (uint32_t)f2b(c.w) | ((uint32_t)f2b(s.w) << 16) };
    ((u32x4*)csB)[off] = o;
    return;
  }
  const float* src; u16* dst; int off;
  if (i < 2097152)      { src = hs; dst = hsB; off = i; }
  else if (i < 3670016) { src = wq; dst = wqB; off = i - 2097152; }
  else                  { src = wo; dst = woB; off = i - 3670016; }
  float4 v = ((const float4*)src)[off];
  uint2 o;
  o.x = (uint32_t)f2b(v.x) | ((uint32_t)f2b(v.y) << 16);
  o.y = (uint32_t)f2b(v.z) | ((uint32_t)f2b(v.w) << 16);
  ((uint2*)dst)[off] = o;
}

// ---- GEMM staging macro: 8 gload_lds (A-tile 4, B-tile 4) into buffer BSEL ----
#define GSTAGE(KT, BSEL) do { \
    _Pragma("unroll") \
    for (int i_ = 0; i_ < 4; ++i_){ \
      const int row_ = (i_ * 4 + w) * 8 + srow; \
      const int gc_ = ((sc ^ (row_ & 7)) << 4); \
      gload_lds16((const char*)A + (size_t)(m0 + row_) * ldb + (size_t)(KT) * 128 + gc_, \
                  (char*)lA + (BSEL) * 16384 + row_ * 128 + sc * 16); \
    } \
    _Pragma("unroll") \
    for (int i_ = 0; i_ < 4; ++i_){ \
      const int row_ = (i_ * 4 + w) * 8 + srow; \
      const int gc_ = ((sc ^ (row_ & 7)) << 4); \
      gload_lds16((const char*)Bm + (size_t)(n0 + row_) * ldb + (size_t)(KT) * 128 + gc_, \
                  (char*)lB + (BSEL) * 16384 + row_ * 128 + sc * 16); \
    } \
  } while (0)

// ---------------- bf16 GEMM (f32 out): C = A * B^T, prefetch-pipelined ----------------
// Double-buffered LDS (64KB); STAGE(kt+1) issued before compute(kt);
// counted vmcnt(8) (attn-verified pattern) — no mid-loop vmcnt(0) drain.
// 1D grid with bijective XCD swizzle (nwg % 8 == 0).
__global__ __launch_bounds__(256)
void gemm_bt_f32(const u16* __restrict__ A, const u16* __restrict__ Bm,
                 float* __restrict__ Cp, int N, int K, int nbx, int nwg)
{
  __shared__ alignas(16) u16 lA[2 * 128 * 64];
  __shared__ alignas(16) u16 lB[2 * 128 * 64];
  const int id = blockIdx.x;
  const int swz = (id & 7) * (nwg >> 3) + (id >> 3);
  const int m0 = (swz / nbx) * 128, n0 = (swz % nbx) * 128;
  const int tid = threadIdx.x;
  const int w = tid >> 6, l = tid & 63;
  const int lg = l >> 4, lc = l & 15;
  const int wm = w >> 1, wn = w & 1;
  const int srow = l >> 3, sc = l & 7;
  const size_t ldb = (size_t)K * 2;   // row bytes
  f32x4 acc[4][4] = {};
  const int kiters = K >> 6;

  GSTAGE(0, 0);
  for (int kt = 0; kt < kiters; ++kt){
    const int cur = kt & 1;
    if (kt + 1 < kiters){
      GSTAGE(kt + 1, cur ^ 1);
      asm volatile("s_waitcnt vmcnt(8)" ::: "memory");   // tile-kt loads landed
    } else {
      asm volatile("s_waitcnt vmcnt(0)" ::: "memory");
    }
    __builtin_amdgcn_s_barrier();
#pragma unroll
    for (int kk = 0; kk < 2; ++kk){
      short8 af[4], bfr[4];
#pragma unroll
      for (int mi = 0; mi < 4; ++mi){
        const int row = wm * 64 + mi * 16 + lc;
        const int cc = (kk * 4 + lg) ^ (row & 7);
        af[mi] = *(const short8*)((const char*)lA + cur * 16384 + row * 128 + cc * 16);
      }
#pragma unroll
      for (int ni = 0; ni < 4; ++ni){
        const int row = wn * 64 + ni * 16 + lc;
        const int cc = (kk * 4 + lg) ^ (row & 7);
        bfr[ni] = *(const short8*)((const char*)lB + cur * 16384 + row * 128 + cc * 16);
      }
#pragma unroll
      for (int mi = 0; mi < 4; ++mi)
#pragma unroll
        for (int ni = 0; ni < 4; ++ni)
          acc[mi][ni] = __builtin_amdgcn_mfma_f32_16x16x32_bf16(af[mi], bfr[ni], acc[mi][ni], 0, 0, 0);
    }
    __builtin_amdgcn_s_barrier();
  }
  const int r0 = m0 + wm * 64 + lg * 4;
  const int c0 = n0 + wn * 64 + lc;
#pragma unroll
  for (int mi = 0; mi < 4; ++mi)
#pragma unroll
    for (int ni = 0; ni < 4; ++ni)
#pragma unroll
      for (int j = 0; j < 4; ++j)
        Cp[(size_t)(r0 + mi * 16 + j) * (size_t)N + (size_t)(c0 + ni * 16)] = acc[mi][ni][j];
}

// ---------------- GEMM1 + fused RoPE/scale epilogue (prefetch-pipelined) ----------------
// qkv = hs * Wqkv^T (M=4096, N=3072, K=2048). Epilogue: per thread one head,
// RoPE partner d^32 = acc[mi][ni^2][j] (same thread). Q *1.2*kscale*phs ->
// Qb; K *1.2 -> Kb; V raw -> Vraw[b][s][8][64]. cs table: bf16 cos|sin.
__global__ __launch_bounds__(256)
void gemm1_rope(const u16* __restrict__ A, const u16* __restrict__ Bm,
                const uint32_t* __restrict__ cs, const float* __restrict__ phs,
                u16* __restrict__ Qo, u16* __restrict__ Ko, u16* __restrict__ Vraw)
{
  __shared__ alignas(16) u16 lA[2 * 128 * 64];
  __shared__ alignas(16) u16 lB[2 * 128 * 64];
  const int id = blockIdx.x;
  const int swz = (id & 7) * 96 + (id >> 3);   // nwg = 768
  const int m0 = (swz / 24) * 128, n0 = (swz % 24) * 128;
  const int tid = threadIdx.x;
  const int w = tid >> 6, l = tid & 63;
  const int lg = l >> 4, lc = l & 15;
  const int wm = w >> 1, wn = w & 1;
  const int srow = l >> 3, sc = l & 7;
  const size_t ldb = 4096;            // K=2048 row bytes
  f32x4 acc[4][4] = {};

  GSTAGE(0, 0);
  for (int kt = 0; kt < 32; ++kt){
    const int cur = kt & 1;
    if (kt + 1 < 32){
      GSTAGE(kt + 1, cur ^ 1);
      asm volatile("s_waitcnt vmcnt(8)" ::: "memory");
    } else {
      asm volatile("s_waitcnt vmcnt(0)" ::: "memory");
    }
    __builtin_amdgcn_s_barrier();
#pragma unroll
    for (int kk = 0; kk < 2; ++kk){
      short8 af[4], bfr[4];
#pragma unroll
      for (int mi = 0; mi < 4; ++mi){
        const int row = wm * 64 + mi * 16 + lc;
        const int cc = (kk * 4 + lg) ^ (row & 7);
        af[mi] = *(const short8*)((const char*)lA + cur * 16384 + row * 128 + cc * 16);
      }
#pragma unroll
      for (int ni = 0; ni < 4; ++ni){
        const int row = wn * 64 + ni * 16 + lc;
        const int cc = (kk * 4 + lg) ^ (row & 7);
        bfr[ni] = *(const short8*)((const char*)lB + cur * 16384 + row * 128 + cc * 16);
      }
#pragma unroll
      for (int mi = 0; mi < 4; ++mi)
#pragma unroll
        for (int ni = 0; ni < 4; ++ni)
          acc[mi][ni] = __builtin_amdgcn_mfma_f32_16x16x32_bf16(af[mi], bfr[ni], acc[mi][ni], 0, 0, 0);
    }
    __builtin_amdgcn_s_barrier();
  }
  const int r0 = m0 + wm * 64 + lg * 4;
  const int c0 = n0 + wn * 64 + lc;
  const int head = (n0 + wn * 64) >> 6;          // one head per thread
  const int b = m0 >> 11;
  if (head < 40){
    const float scale = (head < NQH) ? 1.2f * 0.18033688011112042f * phs[b * NQH + head] : 1.2f;
    u16* dstbase = (head < NQH)
        ? (Qo + ((size_t)(b * NQH + head) * S_LEN) * 64)
        : (Ko + ((size_t)(b * NKH + (head - NQH)) * S_LEN) * 64);
#pragma unroll
    for (int mi = 0; mi < 4; ++mi)
#pragma unroll
      for (int j = 0; j < 4; ++j){
        const int s = (r0 + mi * 16 + j) & 2047;
        const uint32_t* csrow = cs + s * 64;
        float xs[4] = {acc[mi][0][j], acc[mi][1][j], acc[mi][2][j], acc[mi][3][j]};
#pragma unroll
        for (int ni = 0; ni < 4; ++ni){
          const int d = lc + ni * 16;
          const uint32_t csv = csrow[d];
          const float cv = b2f((u16)(csv & 0xffff));
          const float sv = b2f((u16)(csv >> 16));
          const float sgn = (ni < 2) ? -1.f : 1.f;
          const float v = (xs[ni] * cv + sgn * xs[ni ^ 2] * sv) * scale;
          dstbase[(size_t)s * 64 + d] = f2b(v);
        }
      }
  } else {
    // V heads -> compact Vraw[b][s][8][64]
#pragma unroll
    for (int mi = 0; mi < 4; ++mi)
#pragma unroll
      for (int ni = 0; ni < 4; ++ni)
#pragma unroll
        for (int j = 0; j < 4; ++j){
          const int r = r0 + mi * 16 + j;
          Vraw[(size_t)r * 512 + (c0 + ni * 16 - 2560)] = f2b(acc[mi][ni][j]);
        }
  }
}
#undef GSTAGE

// ---------------- V transpose + k-permute: Vraw[b][s][8][64] -> VT[b][kh][d][t*128+k] ----------------
// VT[d][t*128+k] = V[s = t*128 + h(k)][d], h(k) = 32*(k>>5) + 16*((k>>2)&1)
// + 4*((k>>3)&3) + (k&3) -> zero-shuffle PV in attention.
__global__ __launch_bounds__(256)
void vtrans(const u16* __restrict__ Vraw, u16* __restrict__ VT)
{
  int bid = blockIdx.x;                 // (b*8+kh)*16 + t
  int t = bid & 15, kh = (bid >> 4) & 7, b = bid >> 7;
  __shared__ u16 vlds[128][72];
  int tid = threadIdx.x;
  {
    int r = tid >> 1, half = tid & 1;
    const u16* src = Vraw + (((size_t)(b * S_LEN + t * 128 + r) * 8 + kh) << 6) + half * 32;
    uint4 a0 = *(const uint4*)(src);
    uint4 a1 = *(const uint4*)(src + 8);
    uint4 a2 = *(const uint4*)(src + 16);
    uint4 a3 = *(const uint4*)(src + 24);
    *(uint4*)&vlds[r][half * 32]      = a0;
    *(uint4*)&vlds[r][half * 32 + 8]  = a1;
    *(uint4*)&vlds[r][half * 32 + 16] = a2;
    *(uint4*)&vlds[r][half * 32 + 24] = a3;
  }
  __syncthreads();
  const int d = tid >> 2, kk2 = tid & 3;
  u16* dst = VT + ((size_t)(b * NKH + kh) * 64 + d) * S_LEN + t * 128 + kk2 * 32;
#pragma unroll
  for (int j = 0; j < 4; ++j){          // j = lg
    u16 o[8];
#pragma unroll
    for (int e = 0; e < 8; ++e){
      const int hk = kk2 * 32 + ((e >> 2) << 4) + j * 4 + (e & 3);
      o[e] = vlds[hk][d];
    }
    uint4 ov = { (uint32_t)o[0] | ((uint32_t)o[1] << 16), (uint32_t)o[2] | ((uint32_t)o[3] << 16),
                 (uint32_t)o[4] | ((uint32_t)o[5] << 16), (uint32_t)o[6] | ((uint32_t)o[7] << 16) };
    *(uint4*)(dst + j * 8) = ov;
  }
}

// ---------------- attention helper: softmax + pack (zero-shuffle PV) ----------------
__device__ __forceinline__ void proc_chunk(f32x4 (&sv)[8], float& mrow, float& lsum,
                                           f32x4 (&o)[4], uint32_t (&pw)[4][4],
                                           const int lg, const int lc,
                                           const bool diag, const int qloc)
{
  if (diag){
#pragma unroll
    for (int nj = 0; nj < 8; ++nj)
#pragma unroll
      for (int jj = 0; jj < 4; ++jj){
        const int kloc = nj * 16 + lg * 4 + jj;
        if (kloc > qloc) sv[nj][jj] = MNEG;
      }
  }
  float mu = sv[0][0];
#pragma unroll
  for (int nj = 0; nj < 8; ++nj)
#pragma unroll
    for (int jj = 0; jj < 4; ++jj) mu = fmaxf(mu, sv[nj][jj]);
  mu = fmaxf(mu, __shfl_xor(mu, 16));
  mu = fmaxf(mu, __shfl_xor(mu, 32));
  if (!__all(mu <= mrow + 11.54f)){
    const float mnew = fmaxf(mrow, mu);
    const float sf = __builtin_amdgcn_exp2f(mrow - mnew);
    mrow = mnew;
    lsum *= sf;
#pragma unroll
    for (int dn = 0; dn < 4; ++dn)
#pragma unroll
      for (int jj = 0; jj < 4; ++jj) o[dn][jj] *= sf;
  }
  const float mcur = mrow;
  float ps = 0.f;
#pragma unroll
  for (int nj = 0; nj < 8; ++nj)
#pragma unroll
    for (int jj = 0; jj < 4; ++jj){
      const float pv = __builtin_amdgcn_exp2f(sv[nj][jj] - mcur);
      sv[nj][jj] = pv;
      ps += pv;
    }
  lsum += ps;
#pragma unroll
  for (int kk2 = 0; kk2 < 4; ++kk2){
    pw[kk2][0] = cvt_pk_bf16(sv[kk2 * 2][0],     sv[kk2 * 2][1]);
    pw[kk2][1] = cvt_pk_bf16(sv[kk2 * 2][2],     sv[kk2 * 2][3]);
    pw[kk2][2] = cvt_pk_bf16(sv[kk2 * 2 + 1][0], sv[kk2 * 2 + 1][1]);
    pw[kk2][3] = cvt_pk_bf16(sv[kk2 * 2 + 1][2], sv[kk2 * 2 + 1][3]);
  }
}

__device__ __forceinline__ short8 pw_frag(const uint32_t* pw){
  u32x4 v = { pw[0], pw[1], pw[2], pw[3] };
  return __builtin_bit_cast(short8, v);
}

// ---------------- causal GQA flash attention (R11-verified) ----------------
__global__ __launch_bounds__(512, 2)
void attn_kernel(const u16* __restrict__ Q, const u16* __restrict__ Kr,
                 const u16* __restrict__ VT, u16* __restrict__ Ao)
{
  int bid = blockIdx.x;
  int p  = bid & 15;
  int gp = (bid >> 4) & 1;
  int kh = (bid >> 5) & 7;
  int b  = bid >> 8;
  const int qt0 = p, qt1 = 31 - p;

  __shared__ alignas(16) u16 lK[2][128 * 64];
  __shared__ alignas(16) u16 lV[2][64 * 128];

  const int tid = threadIdx.x;
  const int hh = tid >> 8;
  const int h  = kh * 4 + gp * 2 + hh;
  const int w  = (tid >> 6) & 3;
  const int l  = tid & 63;
  const int lg = l >> 4, lc = l & 15;

  short8 qf[2][2];
  {
    const u16* qbase = Q + ((size_t)(b * NQH + h) * S_LEN) * 64;
#pragma unroll
    for (int kk = 0; kk < 2; ++kk){
      qf[0][kk] = *(const short8*)(qbase + (size_t)(qt0 * 64 + w * 16 + lc) * 64 + kk * 32 + lg * 8);
      qf[1][kk] = *(const short8*)(qbase + (size_t)(qt1 * 64 + w * 16 + lc) * 64 + kk * 32 + lg * 8);
    }
  }

  const u16* Kb = Kr + (size_t)(b * NKH + kh) * S_LEN * 64;
  const u16* Vb = VT + (size_t)(b * NKH + kh) * 64 * S_LEN;

  f32x4 o[2][4] = {};
  float mrow[2] = {MNEG, MNEG};
  float lsum[2] = {0.f, 0.f};

  const int nt = (qt1 >> 1) + 1;
  const int nt0 = qt0 >> 1;

#define STAGE(T, BSEL) do { \
    _Pragma("unroll") \
    for (int i_ = 0; i_ < 2; ++i_){ \
      const int row_ = i_ * 64 + (tid >> 3); \
      const int ch_  = tid & 7; \
      const int gc_  = ((ch_ ^ (row_ & 7)) << 4); \
      gload_lds16((const char*)(Kb + (size_t)((T) * 128 + row_) * 64) + gc_, \
                  (char*)lK[BSEL] + row_ * 128 + ch_ * 16); \
    } \
    _Pragma("unroll") \
    for (int i_ = 0; i_ < 2; ++i_){ \
      const int row_ = i_ * 32 + (tid >> 4); \
      const int ch_  = tid & 15; \
      const int gc_  = ((ch_ ^ (row_ & 15)) << 4); \
      gload_lds16((const char*)(Vb + (size_t)row_ * S_LEN + (T) * 128) + gc_, \
                  (char*)lV[BSEL] + row_ * 256 + ch_ * 16); \
    } \
  } while (0)

  STAGE(0, 0);

  for (int t = 0; t < nt; ++t){
    const int cur = t & 1;
    const bool act0 = (t <= nt0);
    if (t + 1 < nt){
      STAGE(t + 1, cur ^ 1);
      asm volatile("s_waitcnt vmcnt(4)" ::: "memory");
    } else {
      asm volatile("s_waitcnt vmcnt(0)" ::: "memory");
    }
    __builtin_amdgcn_s_barrier();

    f32x4 sv[2][8] = {};
    __builtin_amdgcn_s_setprio(1);
#pragma unroll
    for (int kk = 0; kk < 2; ++kk){
      short8 kf[8];
#pragma unroll
      for (int nj = 0; nj < 8; ++nj){
        const int row = nj * 16 + lc;
        const int cc = (kk * 4 + lg) ^ (row & 7);
        kf[nj] = *(const short8*)((const char*)lK[cur] + row * 128 + cc * 16);
      }
      if (act0)
#pragma unroll
        for (int nj = 0; nj < 8; ++nj)
          sv[0][nj] = __builtin_amdgcn_mfma_f32_16x16x32_bf16(kf[nj], qf[0][kk], sv[0][nj], 0, 0, 0);
#pragma unroll
      for (int nj = 0; nj < 8; ++nj)
        sv[1][nj] = __builtin_amdgcn_mfma_f32_16x16x32_bf16(kf[nj], qf[1][kk], sv[1][nj], 0, 0, 0);
    }
    __builtin_amdgcn_s_setprio(0);

    uint32_t pw[2][4][4];
    if (act0)
      proc_chunk(sv[0], mrow[0], lsum[0], o[0], pw[0], lg, lc,
                 t == (qt0 >> 1), (qt0 & 1) * 64 + w * 16 + lc);
    proc_chunk(sv[1], mrow[1], lsum[1], o[1], pw[1], lg, lc,
               t == (qt1 >> 1), (qt1 & 1) * 64 + w * 16 + lc);

    __builtin_amdgcn_s_setprio(1);
#pragma unroll
    for (int kk2 = 0; kk2 < 4; ++kk2){
      short8 vf[4];
#pragma unroll
      for (int dn = 0; dn < 4; ++dn){
        const int row = dn * 16 + lc;
        const int cc = (kk2 * 4 + lg) ^ (row & 15);
        vf[dn] = *(const short8*)((const char*)lV[cur] + row * 256 + cc * 16);
      }
      if (act0){
        const short8 pb0 = pw_frag(pw[0][kk2]);
#pragma unroll
        for (int dn = 0; dn < 4; ++dn)
          o[0][dn] = __builtin_amdgcn_mfma_f32_16x16x32_bf16(vf[dn], pb0, o[0][dn], 0, 0, 0);
      }
      const short8 pb1 = pw_frag(pw[1][kk2]);
#pragma unroll
      for (int dn = 0; dn < 4; ++dn)
        o[1][dn] = __builtin_amdgcn_mfma_f32_16x16x32_bf16(vf[dn], pb1, o[1][dn], 0, 0, 0);
    }
    __builtin_amdgcn_s_setprio(0);
    __builtin_amdgcn_s_barrier();
  }
#undef STAGE

#pragma unroll
  for (int c = 0; c < 2; ++c){
    const int qt = c ? qt1 : qt0;
    float ls = lsum[c];
    ls += __shfl_xor(ls, 16);
    ls += __shfl_xor(ls, 32);
    const float inv = 1.f / ls;
    const int sq = qt * 64 + w * 16 + lc;
#pragma unroll
    for (int dn = 0; dn < 4; ++dn){
      uint2 pk;
      pk.x = cvt_pk_bf16(o[c][dn][0] * inv, o[c][dn][1] * inv);
      pk.y = cvt_pk_bf16(o[c][dn][2] * inv, o[c][dn][3] * inv);
      const int col = h * 64 + dn * 16 + lg * 4;
      *(uint2*)&Ao[(size_t)(b * S_LEN + sq) * 2048 + col] = pk;
    }
  }
}

// ---------------- launcher ----------------
extern "C" void kernel_launch(void* const* d_in, const int* in_sizes, int n_in,
                              void* d_out, int out_size, void* d_ws, size_t ws_size,
                              hipStream_t stream)
{
  const float* cosT = (const float*)d_in[0];
  const float* sinT = (const float*)d_in[1];
  const float* hs   = (const float*)d_in[2];
  const float* phs  = (const float*)d_in[3];
  const float* Wqkv = (const float*)d_in[4];
  const float* Wo   = (const float*)d_in[5];
  float* out = (float*)d_out;
  char* ws = (char*)d_ws;

  u16* hsB   = (u16*)(ws);               // 16,777,216 B (aliased as attn_out later)
  u16* WqkvB = (u16*)(ws + 16777216);    // 12,582,912 B
  u16* WoB   = (u16*)(ws + 29360128);    //  8,388,608 B
  u16* Vraw  = (u16*)(ws + 37748736);    //  4,194,304 B
  u16* Qb    = (u16*)(ws + 41943040);    // 16,777,216 B
  u16* Kb    = (u16*)(ws + 58720256);    //  4,194,304 B
  u16* VTb   = (u16*)(ws + 62914560);    //  4,194,304 B
  uint32_t* csB = (uint32_t*)(ws + 67108864); // 524,288 B (total 67,633,152 B)
  u16* Ao    = hsB;                      // hsB dead after GEMM1

  cvt_all<<<18560, 256, 0, stream>>>(hs, Wqkv, Wo, cosT, sinT, hsB, WqkvB, WoB, csB);
  gemm1_rope<<<768, 256, 0, stream>>>(hsB, WqkvB, csB, phs, Qb, Kb, Vraw);
  vtrans<<<256, 256, 0, stream>>>(Vraw, VTb);
  attn_kernel<<<512, 512, 0, stream>>>(Qb, Kb, VTb, Ao);
  gemm_bt_f32<<<512, 256, 0, stream>>>(Ao, WoB, out, 2048, 2048, 16, 512);
}